// Round 7
// baseline (1801.412 us; speedup 1.0000x reference)
//
#include <hip/hip_runtime.h>

typedef __attribute__((ext_vector_type(8))) short bf16x8;
typedef __attribute__((ext_vector_type(4))) float f32x4;
typedef __attribute__((ext_vector_type(2))) float f32x2;

#define T_N 512
#define I_N 512
#define H_N 1024
#define O_N 512
#define NCL 8            // clusters; cluster c = bid&7
#define NMEM 16          // members per cluster; member m = bid>>3
#define BATCH 8          // batch rows per cluster
#define NTHR 512
#define COLS_H 64        // h-cols per member
#define COLS_FC 32       // out-cols per member
#define KW 192           // recurrence K-slice per wave (8*192 = 1536)
#define KWFC 128         // FC K-slice per wave (8*128 = 1024)
#define AP_STRIDE 1544   // A-panel row stride (1536 + 8 pad)
#define AP_ROWS 20       // 16 MFMA rows (8-15 zero) + pad -> ~89KB LDS -> 1 block/CU
#define RST 9            // reduce stride
#define CANARY 0xFFFFFFFFu
#define HS_CAP  20000000 // startup spin cap
#define POLL_CAP 200000  // per-step sweep cap (terminate, never hang)

__device__ __forceinline__ unsigned short f2bf(float f) {
  unsigned int u = __float_as_uint(f);
  u += 0x7fffu + ((u >> 16) & 1u);
  return (unsigned short)(u >> 16);
}
__device__ __forceinline__ bf16x8 cvt8f(const float* __restrict__ p) {
  float4 a = *(const float4*)p;
  float4 b = *(const float4*)(p + 4);
  bf16x8 r;
  r[0] = (short)f2bf(a.x); r[1] = (short)f2bf(a.y);
  r[2] = (short)f2bf(a.z); r[3] = (short)f2bf(a.w);
  r[4] = (short)f2bf(b.x); r[5] = (short)f2bf(b.y);
  r[6] = (short)f2bf(b.z); r[7] = (short)f2bf(b.w);
  return r;
}
__device__ __forceinline__ bf16x8 cvt8v(float4 a, float4 b) {
  bf16x8 r;
  r[0] = (short)f2bf(a.x); r[1] = (short)f2bf(a.y);
  r[2] = (short)f2bf(a.z); r[3] = (short)f2bf(a.w);
  r[4] = (short)f2bf(b.x); r[5] = (short)f2bf(b.y);
  r[6] = (short)f2bf(b.z); r[7] = (short)f2bf(b.w);
  return r;
}

// ---- memory-side coherent (sc0 sc1 = bypass L1+L2) — the HW-verified channel ----
__device__ __forceinline__ void st_sc01(unsigned int* p, unsigned int v) {
  asm volatile("global_store_dword %0, %1, off sc0 sc1" :: "v"(p), "v"(v) : "memory");
}
__device__ __forceinline__ void st2_sc01(float* p, f32x2 v) {
  asm volatile("global_store_dwordx2 %0, %1, off sc0 sc1" :: "v"(p), "v"(v) : "memory");
}
__device__ __forceinline__ void st2u_sc01(float* p, unsigned long long v) {
  asm volatile("global_store_dwordx2 %0, %1, off sc0 sc1" :: "v"(p), "v"(v) : "memory");
}
__device__ __forceinline__ unsigned int ld_sc01(const unsigned int* p) {
  unsigned int r;
  asm volatile("global_load_dword %0, %1, off sc0 sc1\n\ts_waitcnt vmcnt(0)"
               : "=v"(r) : "v"(p) : "memory");
  return r;
}
__device__ __forceinline__ void ld4_sc01(uint4* d, const void* p) {
  asm volatile("global_load_dwordx4 %0, %1, off sc0 sc1" : "=v"(*d) : "v"(p) : "memory");
}
__device__ __forceinline__ void ld4_rawf(float4* d, const void* p) {
  asm volatile("global_load_dwordx4 %0, %1, off" : "=v"(*d) : "v"(p) : "memory");
}

// Fused persistent RNN, canary-ring exchange.
// Grid 128 = 8 clusters x 16 members; 512 thr (8 waves). Cluster c: batches
// [8c,8c+8); member m: h-cols [64m,64m+64), out-cols [32m,32m+32).
// h exchange: fp32, 4-slot ring, slot t%4; readers poll data for non-CANARY
// (tanhf output can never be 0xFFFFFFFF). Writer at step t also re-canaries
// slot (t+2)%4 (drained by its own next poll's vmcnt(0) before h_{t+1} issues).
// No flags, no fences, no drain on the critical path. All sc1. Spins capped.
__global__ __launch_bounds__(NTHR, 2) void rnn_fused(
    const float* __restrict__ x, const float* __restrict__ hidden,
    const float* __restrict__ Wih, const float* __restrict__ Whh,
    const float* __restrict__ bih, const float* __restrict__ bhh,
    const float* __restrict__ Wfc, const float* __restrict__ bfc,
    float* __restrict__ out, float* __restrict__ hlast,
    float* __restrict__ hslot, unsigned int* __restrict__ flags)
{
  __shared__ __align__(16) unsigned short Apan[AP_ROWS * AP_STRIDE];  // 61760 B
  __shared__ __align__(16) float R [8 * COLS_H  * RST];               // 18432 B
  __shared__ __align__(16) float R2[8 * COLS_FC * RST];               //  9216 B

  const int tid = threadIdx.x;
  const int l = tid & 63, wv = tid >> 6;
  const int bid = blockIdx.x;
  const int c = bid & 7;
  const int m = bid >> 3;
  const int b0 = c * BATCH;
  const int cbh = m * COLS_H;
  const int cbfc = m * COLS_FC;
  float* slotc = hslot + (size_t)c * 4 * BATCH * H_N;   // [4][8][1024] fp32

  // ---------------- persistent weight fragments ----------------
  bf16x8 Bh[6][4];
  {
    const int kb0 = wv * KW + ((l >> 4) << 3);
#pragma unroll
    for (int kst = 0; kst < 6; ++kst) {
      const int k = kb0 + kst * 32;
#pragma unroll
      for (int f = 0; f < 4; ++f) {
        const int col = cbh + f * 16 + (l & 15);
        const float* src = (k < H_N) ? (Whh + (size_t)col * H_N + k)
                                     : (Wih + (size_t)col * I_N + (k - H_N));
        Bh[kst][f] = cvt8f(src);
      }
    }
  }
  bf16x8 Bf[4][2];
  {
    const int kb0 = wv * KWFC + ((l >> 4) << 3);
#pragma unroll
    for (int kst = 0; kst < 4; ++kst)
#pragma unroll
      for (int f = 0; f < 2; ++f)
        Bf[kst][f] = cvt8f(Wfc + (size_t)(cbfc + f * 16 + (l & 15)) * H_N + kb0 + kst * 32);
  }

  // reduce-lane constants (tid<256 paths)
  const int rrow = (tid >> 5) & 7;
  const int rcp  = tid & 31;
  const float pb0 = bih[cbh + 2 * rcp]     + bhh[cbh + 2 * rcp];
  const float pb1 = bih[cbh + 2 * rcp + 1] + bhh[cbh + 2 * rcp + 1];
  const float bfv = bfc[cbfc + rcp];

  // ---- zero MFMA rows 8-15 of A panel ----
  for (int q = tid; q < (8 * AP_STRIDE) / 4; q += NTHR)
    ((unsigned long long*)(Apan + 8 * AP_STRIDE))[q] = 0ULL;
  // ---- stage hidden rows 0-7 (fp32->bf16) ----
  {
    int q = tid;
#pragma unroll
    for (int i = 0; i < 2; ++i, q += NTHR) {
      const int row = q >> 7, col8 = (q & 127) << 3;
      *(bf16x8*)(Apan + row * AP_STRIDE + col8) =
          cvt8f(hidden + (size_t)(b0 + row) * H_N + col8);
    }
  }
  // ---- stage x_0 ----
  {
    const int row = tid >> 6, col8 = (tid & 63) << 3;
    *(bf16x8*)(Apan + row * AP_STRIDE + H_N + col8) =
        cvt8f(x + (size_t)(b0 + row) * I_N + col8);
  }
  // ---- prefetch x_1 (waves 4-7) ----
  float4 xf0, xf1, xf2, xf3;
  if (wv >= 4) {
    const int u = tid & 255;
    const float* p0 = x + ((size_t)64 + b0 + (u >> 6)) * I_N + ((u & 63) << 3);
    ld4_rawf(&xf0, p0); ld4_rawf(&xf1, p0 + 4);
    ld4_rawf(&xf2, p0 + 4 * I_N); ld4_rawf(&xf3, p0 + 4 * I_N + 4);
  }

  // ---- startup: canary own slices of all 4 slots, then one flag barrier ----
  if (tid < 256) {
#pragma unroll
    for (int s = 0; s < 4; ++s)
      st2u_sc01(slotc + (size_t)(s * BATCH + rrow) * H_N + cbh + 2 * rcp,
                0xFFFFFFFFFFFFFFFFull);
  }
  asm volatile("s_waitcnt vmcnt(0)" ::: "memory");
  __syncthreads();
  if (tid == 0) st_sc01(&flags[c * 64 + m], 1u);
  if (tid < NMEM) {
    int it = 0;
    while (ld_sc01(&flags[c * 64 + tid]) < 1u && ++it < HS_CAP)
      if (it > 64) __builtin_amdgcn_s_sleep(1);
  }
  __syncthreads();

  // ========================= steady-state loop =========================
  for (int t = 0; t < T_N; ++t) {
    // ---- MFMA: recurrence (h_t) + FC(t-1) ----
    {
      f32x4 acc[4] = {};
      const int abase = (l & 15) * AP_STRIDE + wv * KW + ((l >> 4) << 3);
#pragma unroll
      for (int kst = 0; kst < 6; ++kst) {
        bf16x8 a = *(const bf16x8*)(Apan + abase + kst * 32);
#pragma unroll
        for (int f = 0; f < 4; ++f)
          acc[f] = __builtin_amdgcn_mfma_f32_16x16x32_bf16(a, Bh[kst][f], acc[f], 0, 0, 0);
      }
      if (l < 32) {
#pragma unroll
        for (int f = 0; f < 4; ++f)
          *(f32x4*)(R + (size_t)(wv * COLS_H + f * 16 + (l & 15)) * RST + ((l >> 4) << 2)) = acc[f];
      }
    }
    if (t > 0) {
      f32x4 afc[2] = {};
      const int ab2 = (l & 15) * AP_STRIDE + wv * KWFC + ((l >> 4) << 3);
#pragma unroll
      for (int kst = 0; kst < 4; ++kst) {
        bf16x8 a = *(const bf16x8*)(Apan + ab2 + kst * 32);
        afc[0] = __builtin_amdgcn_mfma_f32_16x16x32_bf16(a, Bf[kst][0], afc[0], 0, 0, 0);
        afc[1] = __builtin_amdgcn_mfma_f32_16x16x32_bf16(a, Bf[kst][1], afc[1], 0, 0, 0);
      }
      if (l < 32) {
        *(f32x4*)(R2 + (size_t)(wv * COLS_FC + (l & 15)) * RST + ((l >> 4) << 2)) = afc[0];
        *(f32x4*)(R2 + (size_t)(wv * COLS_FC + 16 + (l & 15)) * RST + ((l >> 4) << 2)) = afc[1];
      }
    }
    __syncthreads();  // S1: partials in R/R2; Apan reads done

    // ---- C: waves 0-3 reduce+tanh+publish+ring-clear; waves 4-7 x staging ----
    if (wv < 4) {
      float v0 = pb0, v1 = pb1;
#pragma unroll
      for (int kk = 0; kk < 8; ++kk) {
        v0 += R[(size_t)(kk * COLS_H + 2 * rcp)     * RST + rrow];
        v1 += R[(size_t)(kk * COLS_H + 2 * rcp + 1) * RST + rrow];
      }
      const float h0 = tanhf(v0), h1 = tanhf(v1);
      f32x2 hv; hv[0] = h0; hv[1] = h1;
      st2_sc01(slotc + (size_t)((t & 3) * BATCH + rrow) * H_N + cbh + 2 * rcp, hv);
      st2u_sc01(slotc + (size_t)(((t + 2) & 3) * BATCH + rrow) * H_N + cbh + 2 * rcp,
                0xFFFFFFFFFFFFFFFFull);
      if (t == T_N - 1) {
        float2 fv; fv.x = h0; fv.y = h1;
        *(float2*)(hlast + (size_t)(b0 + rrow) * H_N + cbh + 2 * rcp) = fv;
      }
    } else {
      if (t + 1 < T_N) {
        asm volatile("s_waitcnt vmcnt(0)" ::: "memory");  // xf arrived
        const int u = tid & 255;
        *(bf16x8*)(Apan + (u >> 6) * AP_STRIDE + H_N + ((u & 63) << 3)) = cvt8v(xf0, xf1);
        *(bf16x8*)(Apan + ((u >> 6) + 4) * AP_STRIDE + H_N + ((u & 63) << 3)) = cvt8v(xf2, xf3);
        if (t + 2 < T_N) {
          const float* p0 = x + ((size_t)(t + 2) * 64 + b0 + (u >> 6)) * I_N + ((u & 63) << 3);
          ld4_rawf(&xf0, p0); ld4_rawf(&xf1, p0 + 4);
          ld4_rawf(&xf2, p0 + 4 * I_N); ld4_rawf(&xf3, p0 + 4 * I_N + 4);
        }
      }
    }

    // ---- F: FC reduce + out(t-1) store (overlaps propagation) ----
    if (t > 0 && tid < 256) {
      float v = bfv;
#pragma unroll
      for (int kk = 0; kk < 8; ++kk)
        v += R2[(size_t)(kk * COLS_FC + rcp) * RST + rrow];
      out[(size_t)((t - 1) * 64 + b0 + rrow) * O_N + cbfc + rcp] = v;
    }

    // ---- P: canary poll sweep of slot t%4 (the sweep IS the h load) ----
    {
      const float* slotR = slotc + (size_t)(t & 3) * BATCH * H_N;
      const uint4* sp = (const uint4*)slotR + tid * 4;  // own 16 words
      uint4 u0, u1, u2, u3;
      int it = 0;
      while (true) {
        ld4_sc01(&u0, sp); ld4_sc01(&u1, sp + 1);
        ld4_sc01(&u2, sp + 2); ld4_sc01(&u3, sp + 3);
        asm volatile("s_waitcnt vmcnt(0)" ::: "memory");  // also drains publish/clear/xf
        const bool bad =
            (u0.x == CANARY) | (u0.y == CANARY) | (u0.z == CANARY) | (u0.w == CANARY) |
            (u1.x == CANARY) | (u1.y == CANARY) | (u1.z == CANARY) | (u1.w == CANARY) |
            (u2.x == CANARY) | (u2.y == CANARY) | (u2.z == CANARY) | (u2.w == CANARY) |
            (u3.x == CANARY) | (u3.y == CANARY) | (u3.z == CANARY) | (u3.w == CANARY);
        if (!bad || ++it >= POLL_CAP) break;
        __builtin_amdgcn_s_sleep(1);
      }
      const int row = tid >> 6, colw = (tid & 63) << 4;
      float4 f0 = *(float4*)&u0, f1 = *(float4*)&u1;
      float4 f2 = *(float4*)&u2, f3 = *(float4*)&u3;
      *(bf16x8*)(Apan + row * AP_STRIDE + colw)     = cvt8v(f0, f1);
      *(bf16x8*)(Apan + row * AP_STRIDE + colw + 8) = cvt8v(f2, f3);
    }
    __syncthreads();  // S2: panel ready for next step
  }

  // ---- tail: FC for t = 511 (panel holds h_511) ----
  {
    f32x4 afc[2] = {};
    const int ab2 = (l & 15) * AP_STRIDE + wv * KWFC + ((l >> 4) << 3);
#pragma unroll
    for (int kst = 0; kst < 4; ++kst) {
      bf16x8 a = *(const bf16x8*)(Apan + ab2 + kst * 32);
      afc[0] = __builtin_amdgcn_mfma_f32_16x16x32_bf16(a, Bf[kst][0], afc[0], 0, 0, 0);
      afc[1] = __builtin_amdgcn_mfma_f32_16x16x32_bf16(a, Bf[kst][1], afc[1], 0, 0, 0);
    }
    if (l < 32) {
      *(f32x4*)(R2 + (size_t)(wv * COLS_FC + (l & 15)) * RST + ((l >> 4) << 2)) = afc[0];
      *(f32x4*)(R2 + (size_t)(wv * COLS_FC + 16 + (l & 15)) * RST + ((l >> 4) << 2)) = afc[1];
    }
    __syncthreads();
    if (tid < 256) {
      float v = bfv;
#pragma unroll
      for (int kk = 0; kk < 8; ++kk)
        v += R2[(size_t)(kk * COLS_FC + rcp) * RST + rrow];
      out[(size_t)(511 * 64 + b0 + rrow) * O_N + cbfc + rcp] = v;
    }
  }
}

extern "C" void kernel_launch(void* const* d_in, const int* in_sizes, int n_in,
                              void* d_out, int out_size, void* d_ws, size_t ws_size,
                              hipStream_t stream) {
  const float* x   = (const float*)d_in[0];
  const float* hid = (const float*)d_in[1];
  const float* Wih = (const float*)d_in[2];
  const float* Whh = (const float*)d_in[3];
  const float* bih = (const float*)d_in[4];
  const float* bhh = (const float*)d_in[5];
  const float* Wfc = (const float*)d_in[6];
  const float* bfc = (const float*)d_in[7];

  float* out   = (float*)d_out;                      // fp32 [T*B][O]
  float* hlast = out + (size_t)32768 * 512;          // fp32 [B][H]

  unsigned int* flags = (unsigned int*)d_ws;                   // 4 KB
  float*        hslot = (float*)((char*)d_ws + 4096);          // 8cl x 4 x 8 x 1024 f32 = 1 MB

  hipMemsetAsync(flags, 0, 4096, stream);
  rnn_fused<<<128, NTHR, 0, stream>>>(x, hid, Wih, Whh, bih, bhh, Wfc, bfc,
                                      out, hlast, hslot, flags);
}

// Round 9
// 1699.279 us; speedup vs baseline: 1.0601x; 1.0601x over previous
//
#include <hip/hip_runtime.h>

typedef __attribute__((ext_vector_type(8))) short bf16x8;
typedef __attribute__((ext_vector_type(4))) float f32x4;

#define T_N 512
#define I_N 512
#define H_N 1024
#define O_N 512
#define NCL 4            // clusters; c = bid&3; 16 batch rows each (2 groups x 8)
#define NMEM 16          // members; m = bid>>2; 64 h-cols each
#define NTHR 512
#define COLS_H 64
#define KW 192           // recurrence K-slice per wave (8*192 = 1536)
#define AP_STRIDE 1544   // A-panel row stride (1536 + 8 pad)
#define RST 9            // reduce-buffer stride
#define CANARY 0xFFFFFFFFu   // bf16 NaN pair; tanh output bits never match
#define HS_CAP 20000000
#define POLL_CAP 200000

__device__ __forceinline__ unsigned short f2bf(float f) {
  unsigned int u = __float_as_uint(f);
  u += 0x7fffu + ((u >> 16) & 1u);
  return (unsigned short)(u >> 16);
}
__device__ __forceinline__ bf16x8 cvt8f(const float* __restrict__ p) {
  float4 a = *(const float4*)p;
  float4 b = *(const float4*)(p + 4);
  bf16x8 r;
  r[0] = (short)f2bf(a.x); r[1] = (short)f2bf(a.y);
  r[2] = (short)f2bf(a.z); r[3] = (short)f2bf(a.w);
  r[4] = (short)f2bf(b.x); r[5] = (short)f2bf(b.y);
  r[6] = (short)f2bf(b.z); r[7] = (short)f2bf(b.w);
  return r;
}
__device__ __forceinline__ bf16x8 cvt8v(float4 a, float4 b) {
  bf16x8 r;
  r[0] = (short)f2bf(a.x); r[1] = (short)f2bf(a.y);
  r[2] = (short)f2bf(a.z); r[3] = (short)f2bf(a.w);
  r[4] = (short)f2bf(b.x); r[5] = (short)f2bf(b.y);
  r[6] = (short)f2bf(b.z); r[7] = (short)f2bf(b.w);
  return r;
}

// memory-side coherent channel (bypass L1+L2) — the only HW-proven path (R4/R7)
__device__ __forceinline__ void st_sc01(unsigned int* p, unsigned int v) {
  asm volatile("global_store_dword %0, %1, off sc0 sc1" :: "v"(p), "v"(v) : "memory");
}
__device__ __forceinline__ unsigned int ld_sc01(const unsigned int* p) {
  unsigned int r;
  asm volatile("global_load_dword %0, %1, off sc0 sc1\n\ts_waitcnt vmcnt(0)"
               : "=v"(r) : "v"(p) : "memory");
  return r;
}
__device__ __forceinline__ void ld4_sc01(uint4* d, const void* p) {
  asm volatile("global_load_dwordx4 %0, %1, off sc0 sc1" : "=v"(*d) : "v"(p) : "memory");
}
__device__ __forceinline__ void ld4_rawf(float4* d, const void* p) {
  asm volatile("global_load_dwordx4 %0, %1, off" : "=v"(*d) : "v"(p) : "memory");
}
__device__ __forceinline__ bool has_canary(uint4 a, uint4 b) {
  return (a.x == CANARY) | (a.y == CANARY) | (a.z == CANARY) | (a.w == CANARY) |
         (b.x == CANARY) | (b.y == CANARY) | (b.z == CANARY) | (b.w == CANARY);
}

// One phase of the 2-way interleaved scan (G = 0:rows 0-7 / 1:rows 8-15).
// Publishes group G step t; sweeps the OTHER group's latest publish (one
// phase of sc1-propagation already elapsed) and stages it for the phase
// after next. Ring safety: slot s of ring G is canaried at phase (G,s-2);
// any reader polling it is gated (via the sweep chain) behind that phase's
// vmcnt(0) drain, so pre-canary stale data can never be observed.
#define PHASE(G, X0, X1, X2, X3)                                               \
  {                                                                            \
    f32x4 acc0 = {}, acc1 = {}, acc2 = {}, acc3 = {};                          \
    const int abase = (l & 15) * AP_STRIDE + wv * KW + ((l >> 4) << 3);        \
    _Pragma("unroll")                                                          \
    for (int kst = 0; kst < 6; ++kst) {                                        \
      bf16x8 a = *(const bf16x8*)(Apan + abase + kst * 32);                    \
      acc0 = __builtin_amdgcn_mfma_f32_16x16x32_bf16(a, Bh[kst][0], acc0,0,0,0);\
      acc1 = __builtin_amdgcn_mfma_f32_16x16x32_bf16(a, Bh[kst][1], acc1,0,0,0);\
      acc2 = __builtin_amdgcn_mfma_f32_16x16x32_bf16(a, Bh[kst][2], acc2,0,0,0);\
      acc3 = __builtin_amdgcn_mfma_f32_16x16x32_bf16(a, Bh[kst][3], acc3,0,0,0);\
    }                                                                          \
    if ((l >> 5) == (G)) {  /* rows of group G live in these lanes */          \
      const int rb = ((l >> 4) & 1) << 2;                                      \
      *(f32x4*)(R + (size_t)(wv * COLS_H +  0 + (l & 15)) * RST + rb) = acc0;  \
      *(f32x4*)(R + (size_t)(wv * COLS_H + 16 + (l & 15)) * RST + rb) = acc1;  \
      *(f32x4*)(R + (size_t)(wv * COLS_H + 32 + (l & 15)) * RST + rb) = acc2;  \
      *(f32x4*)(R + (size_t)(wv * COLS_H + 48 + (l & 15)) * RST + rb) = acc3;  \
    }                                                                          \
    __syncthreads();                                                           \
    if (wv < 4) {                                                              \
      float v0 = pb0, v1 = pb1;                                                \
      _Pragma("unroll")                                                        \
      for (int kk = 0; kk < 8; ++kk) {                                         \
        v0 += R[(size_t)(kk * COLS_H + 2 * rcp)     * RST + rrow];             \
        v1 += R[(size_t)(kk * COLS_H + 2 * rcp + 1) * RST + rrow];             \
      }                                                                        \
      const float h0 = tanhf(v0), h1 = tanhf(v1);                              \
      const unsigned int pk =                                                  \
          (unsigned int)f2bf(h0) | ((unsigned int)f2bf(h1) << 16);             \
      st_sc01(ringc + ((G) * 4 + (t & 3)) * 4096 + pubdw, pk);                 \
      st_sc01(ringc + ((G) * 4 + ((t + 2) & 3)) * 4096 + pubdw, CANARY);       \
      *(unsigned int*)(hs + ((size_t)t * 64 + b0 + (G) * 8 + rrow) * H_N +     \
                       cbh + 2 * rcp) = pk;                                    \
      if (t == T_N - 1) {                                                      \
        float2 fv; fv.x = h0; fv.y = h1;                                       \
        *(float2*)(hlast + (size_t)(b0 + (G) * 8 + rrow) * H_N + cbh + 2 * rcp) = fv; \
      }                                                                        \
    } else if (t + 1 < T_N) {  /* waves 4-7: stage x^G_{t+1} */                \
      asm volatile("s_waitcnt vmcnt(0)" ::: "memory");                         \
      const int u = tid & 255;                                                 \
      *(bf16x8*)(Apan + ((G) * 8 + (u >> 6)) * AP_STRIDE + H_N + ((u & 63) << 3)) = \
          cvt8v(X0, X1);                                                       \
      *(bf16x8*)(Apan + ((G) * 8 + (u >> 6) + 4) * AP_STRIDE + H_N + ((u & 63) << 3)) = \
          cvt8v(X2, X3);                                                       \
    }                                                                          \
    if (!((G) == 0 && t == 0)) {  /* sweep other group's latest slot */        \
      const int swt = t - 1 + (G);                                             \
      const unsigned int* sl = ringc + (((G) ^ 1) * 4 + (swt & 3)) * 4096;     \
      const uint4* sp = (const uint4*)sl + (tid << 1);                         \
      uint4 u0, u1; int it = 0;                                                \
      while (true) {                                                           \
        ld4_sc01(&u0, sp); ld4_sc01(&u1, sp + 1);                              \
        asm volatile("s_waitcnt vmcnt(0)" ::: "memory");                       \
        if (!has_canary(u0, u1) || ++it >= POLL_CAP) break;                    \
        __builtin_amdgcn_s_sleep(1);                                           \
      }                                                                        \
      const int prow = (((G) ^ 1) * 8) + (tid >> 6), pcol = (tid & 63) << 4;   \
      *(uint4*)(Apan + prow * AP_STRIDE + pcol)     = u0;                      \
      *(uint4*)(Apan + prow * AP_STRIDE + pcol + 8) = u1;                      \
    }                                                                          \
    if (wv >= 4 && t + 2 < T_N) {  /* prefetch x^G_{t+2} */                    \
      const int u = tid & 255;                                                 \
      const float* px = x + ((size_t)(t + 2) * 64 + b0 + (G) * 8 + (u >> 6)) * I_N + \
                        ((u & 63) << 3);                                       \
      ld4_rawf(&X0, px); ld4_rawf(&X1, px + 4);                                \
      ld4_rawf(&X2, px + 4 * I_N); ld4_rawf(&X3, px + 4 * I_N + 4);            \
    }                                                                          \
    __syncthreads();                                                           \
  }

// Interleaved persistent scan. Grid 64 = 4 clusters x 16 members, 512 thr.
// Cluster c: batches [16c,16c+16) as groups A=[+0,+8) B=[+8,+16).
// Writes hs (bf16, [T][64][H]) and hlast (fp32). FC done by gemm_fc after.
__global__ __launch_bounds__(NTHR, 2) void rnn_scan(
    const float* __restrict__ x, const float* __restrict__ hidden,
    const float* __restrict__ Wih, const float* __restrict__ Whh,
    const float* __restrict__ bih, const float* __restrict__ bhh,
    unsigned short* __restrict__ hs, float* __restrict__ hlast,
    unsigned int* __restrict__ ring, unsigned int* __restrict__ flags)
{
  __shared__ __align__(16) unsigned short Apan[16 * AP_STRIDE];  // 49408 B
  __shared__ __align__(16) float R[8 * COLS_H * RST];            // 18432 B

  const int tid = threadIdx.x;
  const int l = tid & 63, wv = tid >> 6;
  const int bid = blockIdx.x;
  const int c = bid & 3;
  const int m = bid >> 2;
  const int b0 = c * 16;
  const int cbh = m * COLS_H;
  unsigned int* ringc = ring + (size_t)c * 2 * 4 * 4096;  // [2 grp][4 slot][4096 dw]
  unsigned int* bar = flags + c * 64;

  // ---- persistent recurrence weights: K=1536 = [Whh | Wih], 64 cols ----
  bf16x8 Bh[6][4];
  {
    const int kb0 = wv * KW + ((l >> 4) << 3);
#pragma unroll
    for (int kst = 0; kst < 6; ++kst) {
      const int k = kb0 + kst * 32;
#pragma unroll
      for (int f = 0; f < 4; ++f) {
        const int col = cbh + f * 16 + (l & 15);
        const float* src = (k < H_N) ? (Whh + (size_t)col * H_N + k)
                                     : (Wih + (size_t)col * I_N + (k - H_N));
        Bh[kst][f] = cvt8f(src);
      }
    }
  }
  const int rrow = (tid >> 5) & 7;
  const int rcp  = tid & 31;
  const float pb0 = bih[cbh + 2 * rcp]     + bhh[cbh + 2 * rcp];
  const float pb1 = bih[cbh + 2 * rcp + 1] + bhh[cbh + 2 * rcp + 1];
  const int pubdw = rrow * 512 + m * 32 + rcp;

  // ---- stage hidden rows 0-15 (both groups) ----
  {
    int q = tid;
#pragma unroll
    for (int i = 0; i < 4; ++i, q += NTHR) {
      const int row = q >> 7, col8 = (q & 127) << 3;
      *(bf16x8*)(Apan + row * AP_STRIDE + col8) =
          cvt8f(hidden + (size_t)(b0 + row) * H_N + col8);
    }
  }
  // ---- stage x_0 rows 0-15 ----
  {
    int q = tid;
#pragma unroll
    for (int i = 0; i < 2; ++i, q += NTHR) {
      const int row = q >> 6, col8 = (q & 63) << 3;
      *(bf16x8*)(Apan + row * AP_STRIDE + H_N + col8) =
          cvt8f(x + (size_t)(b0 + row) * I_N + col8);
    }
  }
  // ---- canary all 4 slots of both rings (own columns) ----
  if (tid < 256) {
#pragma unroll
    for (int s = 0; s < 8; ++s) st_sc01(ringc + s * 4096 + pubdw, CANARY);
  }
  asm volatile("s_waitcnt vmcnt(0)" ::: "memory");
  __syncthreads();
  // ---- member barrier (sc1 flags, capped) ----
  if (tid == 0) st_sc01(&bar[m], 1u);
  if (tid < NMEM) {
    int it = 0;
    while (ld_sc01(&bar[tid]) < 1u && ++it < HS_CAP)
      if (it > 64) __builtin_amdgcn_s_sleep(1);
  }
  // ---- prefetch x_1 for both groups (waves 4-7) ----
  float4 xA0, xA1, xA2, xA3, xB0, xB1, xB2, xB3;
  if (wv >= 4) {
    const int u = tid & 255;
    const float* pa = x + (size_t)(64 + b0 + (u >> 6)) * I_N + ((u & 63) << 3);
    ld4_rawf(&xA0, pa); ld4_rawf(&xA1, pa + 4);
    ld4_rawf(&xA2, pa + 4 * I_N); ld4_rawf(&xA3, pa + 4 * I_N + 4);
    const float* pb = x + (size_t)(64 + b0 + 8 + (u >> 6)) * I_N + ((u & 63) << 3);
    ld4_rawf(&xB0, pb); ld4_rawf(&xB1, pb + 4);
    ld4_rawf(&xB2, pb + 4 * I_N); ld4_rawf(&xB3, pb + 4 * I_N + 4);
  }
  __syncthreads();

  for (int t = 0; t < T_N; ++t) {
    PHASE(0, xA0, xA1, xA2, xA3)   // group A step t
    PHASE(1, xB0, xB1, xB2, xB3)   // group B step t
  }
}

// FC GEMM: C[m][n] = sum_k hs[m][k]*Wfcb[n][k] + bfc[n]; fp32 out.
// M=32768, N=512, K=1024. 128x128 block tile, 4 waves, 64x64 wave tiles.
__global__ __launch_bounds__(256) void gemm_fc(const unsigned short* __restrict__ A,
                                               const unsigned short* __restrict__ Bt,
                                               const float* __restrict__ bias,
                                               float* __restrict__ C) {
  const int N = O_N, K = H_N;
  const int bm = blockIdx.x >> 2, bn = blockIdx.x & 3;
  const int l = threadIdx.x & 63, w = threadIdx.x >> 6;
  const int wr = w >> 1, wc = w & 1;
  const int row_a = bm * 128 + wr * 64 + (l & 15);
  const int row_b = bn * 128 + wc * 64 + (l & 15);
  const int koff = (l >> 4) * 8;
  f32x4 acc[4][4] = {};
  for (int k = 0; k < K; k += 32) {
    bf16x8 a[4], b[4];
#pragma unroll
    for (int i = 0; i < 4; i++)
      a[i] = *(const bf16x8*)(A + (size_t)(row_a + i * 16) * K + k + koff);
#pragma unroll
    for (int i = 0; i < 4; i++)
      b[i] = *(const bf16x8*)(Bt + (size_t)(row_b + i * 16) * K + k + koff);
#pragma unroll
    for (int i = 0; i < 4; i++)
#pragma unroll
      for (int j = 0; j < 4; j++)
        acc[i][j] = __builtin_amdgcn_mfma_f32_16x16x32_bf16(a[i], b[j], acc[i][j], 0, 0, 0);
  }
  const int orow = bm * 128 + wr * 64 + ((l >> 4) << 2);
  const int ocol = bn * 128 + wc * 64 + (l & 15);
#pragma unroll
  for (int i = 0; i < 4; i++)
#pragma unroll
    for (int j = 0; j < 4; j++) {
      const int r0 = orow + i * 16, c0 = ocol + j * 16;
      const float bv = bias[c0];
#pragma unroll
      for (int r = 0; r < 4; r++)
        C[(size_t)(r0 + r) * N + c0] = acc[i][j][r] + bv;
    }
}

// fp32 -> bf16 convert (for Wfc)
__global__ __launch_bounds__(256) void cvt8(const float* __restrict__ s,
                                            unsigned short* __restrict__ d, long n) {
  long i = ((long)blockIdx.x * blockDim.x + threadIdx.x) * 8;
  if (i < n) *(bf16x8*)(d + i) = cvt8f(s + i);
}

extern "C" void kernel_launch(void* const* d_in, const int* in_sizes, int n_in,
                              void* d_out, int out_size, void* d_ws, size_t ws_size,
                              hipStream_t stream) {
  const float* x   = (const float*)d_in[0];
  const float* hid = (const float*)d_in[1];
  const float* Wih = (const float*)d_in[2];
  const float* Whh = (const float*)d_in[3];
  const float* bih = (const float*)d_in[4];
  const float* bhh = (const float*)d_in[5];
  const float* Wfc = (const float*)d_in[6];
  const float* bfc = (const float*)d_in[7];

  float* out   = (float*)d_out;                      // fp32 [T*B][O]
  float* hlast = out + (size_t)32768 * 512;          // fp32 [B][H]

  unsigned int*   flags = (unsigned int*)d_ws;                       // 4 KB
  unsigned int*   ring  = (unsigned int*)((char*)d_ws + 4096);       // 512 KB
  unsigned short* Wfcb  = (unsigned short*)((char*)d_ws + 4096 + 524288);  // 1 MB
  unsigned short* hsb   = Wfcb + (size_t)512 * 1024;                 // 67.1 MB

  hipMemsetAsync(flags, 0, 4096, stream);
  cvt8<<<256, 256, 0, stream>>>(Wfc, Wfcb, (long)512 * 1024);
  rnn_scan<<<64, NTHR, 0, stream>>>(x, hid, Wih, Whh, bih, bhh, hsb, hlast, ring, flags);
  gemm_fc<<<1024, 256, 0, stream>>>(hsb, Wfcb, bfc, out);
}

// Round 11
// 1693.975 us; speedup vs baseline: 1.0634x; 1.0031x over previous
//
#include <hip/hip_runtime.h>

typedef __attribute__((ext_vector_type(8))) short bf16x8;
typedef __attribute__((ext_vector_type(4))) float f32x4;

#define T_N 512
#define I_N 512
#define H_N 1024
#define O_N 512
#define NCL 4            // clusters; c = bid&3; 16 batch rows each (2 groups x 8)
#define NMEM 16          // members; m = bid>>2; 64 h-cols each
#define NTHR 512
#define COLS_H 64
#define KW 192           // recurrence K-slice per wave (8*192 = 1536)
#define AP_STRIDE 1544   // A-panel row stride (1536 + 8 pad)
#define RST 9            // reduce-buffer stride
#define CANARY 0xFFFFFFFFu   // bf16 NaN pair; tanh output bits never match
#define HS_CAP 20000000
#define POLL_CAP 200000

__device__ __forceinline__ unsigned short f2bf(float f) {
  unsigned int u = __float_as_uint(f);
  u += 0x7fffu + ((u >> 16) & 1u);
  return (unsigned short)(u >> 16);
}
__device__ __forceinline__ bf16x8 cvt8f(const float* __restrict__ p) {
  float4 a = *(const float4*)p;
  float4 b = *(const float4*)(p + 4);
  bf16x8 r;
  r[0] = (short)f2bf(a.x); r[1] = (short)f2bf(a.y);
  r[2] = (short)f2bf(a.z); r[3] = (short)f2bf(a.w);
  r[4] = (short)f2bf(b.x); r[5] = (short)f2bf(b.y);
  r[6] = (short)f2bf(b.z); r[7] = (short)f2bf(b.w);
  return r;
}
__device__ __forceinline__ bf16x8 cvt8v(float4 a, float4 b) {
  bf16x8 r;
  r[0] = (short)f2bf(a.x); r[1] = (short)f2bf(a.y);
  r[2] = (short)f2bf(a.z); r[3] = (short)f2bf(a.w);
  r[4] = (short)f2bf(b.x); r[5] = (short)f2bf(b.y);
  r[6] = (short)f2bf(b.z); r[7] = (short)f2bf(b.w);
  return r;
}

// memory-side coherent channel (bypass L1+L2) — the only HW-proven path (R4/R7/R9)
__device__ __forceinline__ void st_sc01(unsigned int* p, unsigned int v) {
  asm volatile("global_store_dword %0, %1, off sc0 sc1" :: "v"(p), "v"(v) : "memory");
}
__device__ __forceinline__ void st_raw32(unsigned int* p, unsigned int v) {
  asm volatile("global_store_dword %0, %1, off" :: "v"(p), "v"(v) : "memory");
}
__device__ __forceinline__ unsigned int ld_sc01(const unsigned int* p) {
  unsigned int r;
  asm volatile("global_load_dword %0, %1, off sc0 sc1\n\ts_waitcnt vmcnt(0)"
               : "=v"(r) : "v"(p) : "memory");
  return r;
}
// tied 32-bit load: dest keeps its pre-init (CANARY) until the load COMPLETES.
// Safety net: if any vmcnt miscount lets the check run early, it sees CANARY
// and falls into the re-poll loop -> correctness preserved, perf-only risk.
__device__ __forceinline__ void ld_sc01_rw(unsigned int* d, const unsigned int* p) {
  asm volatile("global_load_dword %0, %1, off sc0 sc1" : "+v"(*d) : "v"(p) : "memory");
}
__device__ __forceinline__ void ld_sc01_nw(unsigned int* d, const unsigned int* p) {
  asm volatile("global_load_dword %0, %1, off sc0 sc1" : "=v"(*d) : "v"(p) : "memory");
}
__device__ __forceinline__ void ld4_rawf(float4* d, const void* p) {
  asm volatile("global_load_dwordx4 %0, %1, off" : "=v"(*d) : "v"(p) : "memory");
}

// One phase of the 2-way interleaved scan (G = 0: rows 0-7 / 1: rows 8-15).
// PIPELINED: 8 coalesced sweep dword-loads (other group's latest publish) are
// issued FIRST into canary-pre-initialized regs, fly under MFMA+reduce+publish,
// and are checked with a counted vmcnt afterwards.
#define PHASE(G, X0, X1, X2, X3)                                               \
  {                                                                            \
    const bool doSweep = !((G) == 0 && t == 0) && !((G) == 1 && t == T_N - 1); \
    unsigned int sw[8];                                                        \
    const unsigned int* spd = ringc;                                           \
    if (doSweep) {                                                             \
      const int swt = t - 1 + (G);                                             \
      spd = ringc + (((G) ^ 1) * 4 + (swt & 3)) * 4096 + tid;                  \
      _Pragma("unroll")                                                        \
      for (int j = 0; j < 8; ++j) {                                            \
        sw[j] = CANARY;                                                        \
        ld_sc01_rw(&sw[j], spd + 512 * j);                                     \
      }                                                                        \
    }                                                                          \
    /* ---- MFMA (reads Apan staged in earlier phases) ---- */                 \
    f32x4 acc0 = {}, acc1 = {}, acc2 = {}, acc3 = {};                          \
    const int abase = (l & 15) * AP_STRIDE + wv * KW + ((l >> 4) << 3);        \
    _Pragma("unroll")                                                          \
    for (int kst = 0; kst < 6; ++kst) {                                        \
      bf16x8 a = *(const bf16x8*)(Apan + abase + kst * 32);                    \
      acc0 = __builtin_amdgcn_mfma_f32_16x16x32_bf16(a, Bh[kst][0], acc0,0,0,0);\
      acc1 = __builtin_amdgcn_mfma_f32_16x16x32_bf16(a, Bh[kst][1], acc1,0,0,0);\
      acc2 = __builtin_amdgcn_mfma_f32_16x16x32_bf16(a, Bh[kst][2], acc2,0,0,0);\
      acc3 = __builtin_amdgcn_mfma_f32_16x16x32_bf16(a, Bh[kst][3], acc3,0,0,0);\
    }                                                                          \
    if ((l >> 5) == (G)) {  /* group G's output rows live in these lanes */    \
      const int rb = ((l >> 4) & 1) << 2;                                      \
      *(f32x4*)(R + (size_t)(wv * COLS_H +  0 + (l & 15)) * RST + rb) = acc0;  \
      *(f32x4*)(R + (size_t)(wv * COLS_H + 16 + (l & 15)) * RST + rb) = acc1;  \
      *(f32x4*)(R + (size_t)(wv * COLS_H + 32 + (l & 15)) * RST + rb) = acc2;  \
      *(f32x4*)(R + (size_t)(wv * COLS_H + 48 + (l & 15)) * RST + rb) = acc3;  \
    }                                                                          \
    __syncthreads();                                                           \
    if (wv < 4) {                                                              \
      float v0 = pb0, v1 = pb1;                                                \
      _Pragma("unroll")                                                        \
      for (int kk = 0; kk < 8; ++kk) {                                         \
        v0 += R[(size_t)(kk * COLS_H + 2 * rcp)     * RST + rrow];             \
        v1 += R[(size_t)(kk * COLS_H + 2 * rcp + 1) * RST + rrow];             \
      }                                                                        \
      const float h0 = tanhf(v0), h1 = tanhf(v1);                              \
      const unsigned int pk =                                                  \
          (unsigned int)f2bf(h0) | ((unsigned int)f2bf(h1) << 16);             \
      /* 3 stores, asm-pinned AFTER the 8 sweep loads */                       \
      st_sc01(ringc + ((G) * 4 + (t & 3)) * 4096 + pubdw, pk);                 \
      st_sc01(ringc + ((G) * 4 + ((t + 2) & 3)) * 4096 + pubdw, CANARY);       \
      st_raw32((unsigned int*)(hs + ((size_t)t * 64 + b0 + (G) * 8 + rrow) * H_N \
                               + cbh + 2 * rcp), pk);                          \
      if (doSweep) {                                                           \
        asm volatile("s_waitcnt vmcnt(3)" ::: "memory");  /* sweeps done; 3 stores fly */ \
        __builtin_amdgcn_sched_barrier(0);                                     \
        bool bad = false;                                                      \
        _Pragma("unroll")                                                      \
        for (int j = 0; j < 8; ++j) bad |= (sw[j] == CANARY);                  \
        if (bad) {                                                             \
          int it = 0;                                                          \
          do {                                                                 \
            _Pragma("unroll")                                                  \
            for (int j = 0; j < 8; ++j) ld_sc01_nw(&sw[j], spd + 512 * j);     \
            asm volatile("s_waitcnt vmcnt(0)" ::: "memory");                   \
            __builtin_amdgcn_sched_barrier(0);                                 \
            bad = false;                                                       \
            _Pragma("unroll")                                                  \
            for (int j = 0; j < 8; ++j) bad |= (sw[j] == CANARY);              \
          } while (bad && ++it < POLL_CAP);                                    \
        }                                                                      \
      }                                                                        \
      if (t == T_N - 1) {                                                      \
        float2 fv; fv.x = h0; fv.y = h1;                                       \
        *(float2*)(hlast + (size_t)(b0 + (G) * 8 + rrow) * H_N + cbh + 2 * rcp) = fv; \
      }                                                                        \
    } else {                                                                   \
      if (t == 0) {  /* drain preamble x loads before staging (see counts) */  \
        if ((G) == 0) asm volatile("s_waitcnt vmcnt(4)" ::: "memory");         \
        else          asm volatile("s_waitcnt vmcnt(8)" ::: "memory");         \
        __builtin_amdgcn_sched_barrier(0);                                     \
      }  /* steady state: prior phase's vmcnt(0) already drained our x loads */ \
      if (t + 1 < T_N) {                                                       \
        const int u = tid & 255;                                               \
        *(bf16x8*)(Apan + ((G) * 8 + (u >> 6)) * AP_STRIDE + H_N + ((u & 63) << 3)) = \
            cvt8v(X0, X1);                                                     \
        *(bf16x8*)(Apan + ((G) * 8 + (u >> 6) + 4) * AP_STRIDE + H_N + ((u & 63) << 3)) = \
            cvt8v(X2, X3);                                                     \
      }                                                                        \
      if (doSweep) {                                                           \
        asm volatile("s_waitcnt vmcnt(0)" ::: "memory");                       \
        __builtin_amdgcn_sched_barrier(0);                                     \
        bool bad = false;                                                      \
        _Pragma("unroll")                                                      \
        for (int j = 0; j < 8; ++j) bad |= (sw[j] == CANARY);                  \
        if (bad) {                                                             \
          int it = 0;                                                          \
          do {                                                                 \
            _Pragma("unroll")                                                  \
            for (int j = 0; j < 8; ++j) ld_sc01_nw(&sw[j], spd + 512 * j);     \
            asm volatile("s_waitcnt vmcnt(0)" ::: "memory");                   \
            __builtin_amdgcn_sched_barrier(0);                                 \
            bad = false;                                                       \
            _Pragma("unroll")                                                  \
            for (int j = 0; j < 8; ++j) bad |= (sw[j] == CANARY);              \
          } while (bad && ++it < POLL_CAP);                                    \
        }                                                                      \
      }                                                                        \
      if (t + 2 < T_N) {  /* prefetch x^G_{t+2}; drained by later vmcnt(0) */  \
        const int u = tid & 255;                                               \
        const float* px = x + ((size_t)(t + 2) * 64 + b0 + (G) * 8 + (u >> 6)) * I_N \
                          + ((u & 63) << 3);                                   \
        ld4_rawf(&X0, px); ld4_rawf(&X1, px + 4);                              \
        ld4_rawf(&X2, px + 4 * I_N); ld4_rawf(&X3, px + 4 * I_N + 4);          \
      }                                                                        \
    }                                                                          \
    if (doSweep) {  /* stage swept h (row j, dword-col tid) for next MFMA */   \
      _Pragma("unroll")                                                        \
      for (int j = 0; j < 8; ++j)                                              \
        *(unsigned int*)(Apan + ((((G) ^ 1) * 8) + j) * AP_STRIDE + (tid << 1)) = sw[j]; \
    }                                                                          \
    __syncthreads();                                                           \
  }

// Interleaved persistent scan. Grid 64 = 4 clusters x 16 members, 512 thr.
// Cluster c: batches [16c,16c+16) as groups A=[+0,+8) B=[+8,+16).
// Writes hs (bf16, [T][64][H]) and hlast (fp32). FC done by gemm_fc after.
__global__ __launch_bounds__(NTHR, 2) void rnn_scan(
    const float* __restrict__ x, const float* __restrict__ hidden,
    const float* __restrict__ Wih, const float* __restrict__ Whh,
    const float* __restrict__ bih, const float* __restrict__ bhh,
    unsigned short* __restrict__ hs, float* __restrict__ hlast,
    unsigned int* __restrict__ ring, unsigned int* __restrict__ flags)
{
  __shared__ __align__(16) unsigned short Apan[16 * AP_STRIDE];  // 49408 B
  __shared__ __align__(16) float R[8 * COLS_H * RST];            // 18432 B

  const int tid = threadIdx.x;
  const int l = tid & 63, wv = tid >> 6;
  const int bid = blockIdx.x;
  const int c = bid & 3;
  const int m = bid >> 2;
  const int b0 = c * 16;
  const int cbh = m * COLS_H;
  unsigned int* ringc = ring + (size_t)c * 2 * 4 * 4096;  // [2 grp][4 slot][4096 dw]
  unsigned int* bar = flags + c * 64;

  // ---- persistent recurrence weights: K=1536 = [Whh | Wih], 64 cols ----
  bf16x8 Bh[6][4];
  {
    const int kb0 = wv * KW + ((l >> 4) << 3);
#pragma unroll
    for (int kst = 0; kst < 6; ++kst) {
      const int k = kb0 + kst * 32;
#pragma unroll
      for (int f = 0; f < 4; ++f) {
        const int col = cbh + f * 16 + (l & 15);
        const float* src = (k < H_N) ? (Whh + (size_t)col * H_N + k)
                                     : (Wih + (size_t)col * I_N + (k - H_N));
        Bh[kst][f] = cvt8f(src);
      }
    }
  }
  const int rrow = (tid >> 5) & 7;
  const int rcp  = tid & 31;
  const float pb0 = bih[cbh + 2 * rcp]     + bhh[cbh + 2 * rcp];
  const float pb1 = bih[cbh + 2 * rcp + 1] + bhh[cbh + 2 * rcp + 1];
  const int pubdw = rrow * 512 + m * 32 + rcp;

  // ---- stage hidden rows 0-15 (both groups) ----
  {
    int q = tid;
#pragma unroll
    for (int i = 0; i < 4; ++i, q += NTHR) {
      const int row = q >> 7, col8 = (q & 127) << 3;
      *(bf16x8*)(Apan + row * AP_STRIDE + col8) =
          cvt8f(hidden + (size_t)(b0 + row) * H_N + col8);
    }
  }
  // ---- stage x_0 rows 0-15 ----
  {
    int q = tid;
#pragma unroll
    for (int i = 0; i < 2; ++i, q += NTHR) {
      const int row = q >> 6, col8 = (q & 63) << 3;
      *(bf16x8*)(Apan + row * AP_STRIDE + H_N + col8) =
          cvt8f(x + (size_t)(b0 + row) * I_N + col8);
    }
  }
  // ---- canary all 4 slots of both rings (own columns) ----
  if (tid < 256) {
#pragma unroll
    for (int s = 0; s < 8; ++s) st_sc01(ringc + s * 4096 + pubdw, CANARY);
  }
  asm volatile("s_waitcnt vmcnt(0)" ::: "memory");
  __syncthreads();
  // ---- member barrier (sc1 flags, capped) ----
  if (tid == 0) st_sc01(&bar[m], 1u);
  if (tid < NMEM) {
    int it = 0;
    while (ld_sc01(&bar[tid]) < 1u && ++it < HS_CAP)
      if (it > 64) __builtin_amdgcn_s_sleep(1);
  }
  // ---- prefetch x_1 for both groups (waves 4-7): xA(4) then xB(4) ----
  float4 xA0, xA1, xA2, xA3, xB0, xB1, xB2, xB3;
  if (wv >= 4) {
    const int u = tid & 255;
    const float* pa = x + (size_t)(64 + b0 + (u >> 6)) * I_N + ((u & 63) << 3);
    ld4_rawf(&xA0, pa); ld4_rawf(&xA1, pa + 4);
    ld4_rawf(&xA2, pa + 4 * I_N); ld4_rawf(&xA3, pa + 4 * I_N + 4);
    const float* pb = x + (size_t)(64 + b0 + 8 + (u >> 6)) * I_N + ((u & 63) << 3);
    ld4_rawf(&xB0, pb); ld4_rawf(&xB1, pb + 4);
    ld4_rawf(&xB2, pb + 4 * I_N); ld4_rawf(&xB3, pb + 4 * I_N + 4);
  }
  __syncthreads();

  for (int t = 0; t < T_N; ++t) {
    PHASE(0, xA0, xA1, xA2, xA3)   // group A step t
    PHASE(1, xB0, xB1, xB2, xB3)   // group B step t
  }
}

// FC GEMM: C[m][n] = sum_k hs[m][k]*Wfcb[n][k] + bfc[n]; fp32 out.
// M=32768, N=512, K=1024. 128x128 block tile, 4 waves, 64x64 wave tiles.
__global__ __launch_bounds__(256) void gemm_fc(const unsigned short* __restrict__ A,
                                               const unsigned short* __restrict__ Bt,
                                               const float* __restrict__ bias,
                                               float* __restrict__ C) {
  const int N = O_N, K = H_N;
  const int bm = blockIdx.x >> 2, bn = blockIdx.x & 3;
  const int l = threadIdx.x & 63, w = threadIdx.x >> 6;
  const int wr = w >> 1, wc = w & 1;
  const int row_a = bm * 128 + wr * 64 + (l & 15);
  const int row_b = bn * 128 + wc * 64 + (l & 15);
  const int koff = (l >> 4) * 8;
  f32x4 acc[4][4] = {};
  for (int k = 0; k < K; k += 32) {
    bf16x8 a[4], b[4];
#pragma unroll
    for (int i = 0; i < 4; i++)
      a[i] = *(const bf16x8*)(A + (size_t)(row_a + i * 16) * K + k + koff);
#pragma unroll
    for (int i = 0; i < 4; i++)
      b[i] = *(const bf16x8*)(Bt + (size_t)(row_b + i * 16) * K + k + koff);
#pragma unroll
    for (int i = 0; i < 4; i++)
#pragma unroll
      for (int j = 0; j < 4; j++)
        acc[i][j] = __builtin_amdgcn_mfma_f32_16x16x32_bf16(a[i], b[j], acc[i][j], 0, 0, 0);
  }
  const int orow = bm * 128 + wr * 64 + ((l >> 4) << 2);
  const int ocol = bn * 128 + wc * 64 + (l & 15);
#pragma unroll
  for (int i = 0; i < 4; i++)
#pragma unroll
    for (int j = 0; j < 4; j++) {
      const int r0 = orow + i * 16, c0 = ocol + j * 16;
      const float bv = bias[c0];
#pragma unroll
      for (int r = 0; r < 4; r++)
        C[(size_t)(r0 + r) * N + c0] = acc[i][j][r] + bv;
    }
}

// fp32 -> bf16 convert (for Wfc)
__global__ __launch_bounds__(256) void cvt8(const float* __restrict__ s,
                                            unsigned short* __restrict__ d, long n) {
  long i = ((long)blockIdx.x * blockDim.x + threadIdx.x) * 8;
  if (i < n) *(bf16x8*)(d + i) = cvt8f(s + i);
}

extern "C" void kernel_launch(void* const* d_in, const int* in_sizes, int n_in,
                              void* d_out, int out_size, void* d_ws, size_t ws_size,
                              hipStream_t stream) {
  const float* x   = (const float*)d_in[0];
  const float* hid = (const float*)d_in[1];
  const float* Wih = (const float*)d_in[2];
  const float* Whh = (const float*)d_in[3];
  const float* bih = (const float*)d_in[4];
  const float* bhh = (const float*)d_in[5];
  const float* Wfc = (const float*)d_in[6];
  const float* bfc = (const float*)d_in[7];

  float* out   = (float*)d_out;                      // fp32 [T*B][O]
  float* hlast = out + (size_t)32768 * 512;          // fp32 [B][H]

  unsigned int*   flags = (unsigned int*)d_ws;                       // 4 KB
  unsigned int*   ring  = (unsigned int*)((char*)d_ws + 4096);       // 512 KB
  unsigned short* Wfcb  = (unsigned short*)((char*)d_ws + 4096 + 524288);  // 1 MB
  unsigned short* hsb   = Wfcb + (size_t)512 * 1024;                 // 67.1 MB

  (void)hipMemsetAsync(flags, 0, 4096, stream);
  cvt8<<<256, 256, 0, stream>>>(Wfc, Wfcb, (long)512 * 1024);
  rnn_scan<<<64, NTHR, 0, stream>>>(x, hid, Wih, Whh, bih, bhh, hsb, hlast, ring, flags);
  gemm_fc<<<1024, 256, 0, stream>>>(hsb, Wfcb, bfc, out);
}

// Round 12
// 1638.458 us; speedup vs baseline: 1.0995x; 1.0339x over previous
//
#include <hip/hip_runtime.h>

typedef __attribute__((ext_vector_type(8))) short bf16x8;
typedef __attribute__((ext_vector_type(4))) float f32x4;

#define T_N 512
#define I_N 512
#define H_N 1024
#define O_N 512
#define NCL 4            // clusters; c = bid&3; 16 batch rows each (2 groups x 8)
#define NMEM 16          // members; m = bid>>2; 64 h-cols each
#define NTHR 512
#define COLS_H 64
#define KW 192           // recurrence K-slice per wave (8*192 = 1536)
#define AP_STRIDE 1544   // A-panel row stride (1536 + 8 pad)
#define RST 9            // reduce-buffer stride
#define CANARY 0xFFFFFFFFu   // bf16 NaN pair; tanh output bits never match
#define HS_CAP 20000000
#define POLL_CAP 200000

__device__ __forceinline__ unsigned short f2bf(float f) {
  unsigned int u = __float_as_uint(f);
  u += 0x7fffu + ((u >> 16) & 1u);
  return (unsigned short)(u >> 16);
}
__device__ __forceinline__ bf16x8 cvt8f(const float* __restrict__ p) {
  float4 a = *(const float4*)p;
  float4 b = *(const float4*)(p + 4);
  bf16x8 r;
  r[0] = (short)f2bf(a.x); r[1] = (short)f2bf(a.y);
  r[2] = (short)f2bf(a.z); r[3] = (short)f2bf(a.w);
  r[4] = (short)f2bf(b.x); r[5] = (short)f2bf(b.y);
  r[6] = (short)f2bf(b.z); r[7] = (short)f2bf(b.w);
  return r;
}
__device__ __forceinline__ bf16x8 cvt8v(float4 a, float4 b) {
  bf16x8 r;
  r[0] = (short)f2bf(a.x); r[1] = (short)f2bf(a.y);
  r[2] = (short)f2bf(a.z); r[3] = (short)f2bf(a.w);
  r[4] = (short)f2bf(b.x); r[5] = (short)f2bf(b.y);
  r[6] = (short)f2bf(b.z); r[7] = (short)f2bf(b.w);
  return r;
}

// RAW workgroup barrier: orders LDS only; vmem (sweeps/publishes/prefetches)
// stays IN FLIGHT across it. This is the whole point of R12 — __syncthreads
// would emit s_waitcnt vmcnt(0) and drain the pipelined sweep loads.
__device__ __forceinline__ void barrier_lds() {
  asm volatile("s_waitcnt lgkmcnt(0)" ::: "memory");
  __builtin_amdgcn_s_barrier();
  __builtin_amdgcn_sched_barrier(0);
}

// memory-side coherent channel (bypass L1+L2) — the only HW-proven path (R4/R7/R9)
__device__ __forceinline__ void st_sc01(unsigned int* p, unsigned int v) {
  asm volatile("global_store_dword %0, %1, off sc0 sc1" :: "v"(p), "v"(v) : "memory");
}
__device__ __forceinline__ void st_raw32(unsigned int* p, unsigned int v) {
  asm volatile("global_store_dword %0, %1, off" :: "v"(p), "v"(v) : "memory");
}
__device__ __forceinline__ unsigned int ld_sc01(const unsigned int* p) {
  unsigned int r;
  asm volatile("global_load_dword %0, %1, off sc0 sc1\n\ts_waitcnt vmcnt(0)"
               : "=v"(r) : "v"(p) : "memory");
  return r;
}
// tied 32-bit load: dest keeps its pre-init (CANARY) until the load COMPLETES.
// Safety net: any vmcnt miscount -> check sees CANARY -> re-poll loop.
__device__ __forceinline__ void ld_sc01_rw(unsigned int* d, const unsigned int* p) {
  asm volatile("global_load_dword %0, %1, off sc0 sc1" : "+v"(*d) : "v"(p) : "memory");
}
__device__ __forceinline__ void ld_sc01_nw(unsigned int* d, const unsigned int* p) {
  asm volatile("global_load_dword %0, %1, off sc0 sc1" : "=v"(*d) : "v"(p) : "memory");
}
__device__ __forceinline__ void ld4_rawf(float4* d, const void* p) {
  asm volatile("global_load_dwordx4 %0, %1, off" : "=v"(*d) : "v"(p) : "memory");
}

// One phase of the 2-way interleaved scan (G = 0: rows 0-7 / 1: rows 8-15).
// 8 coalesced sweep loads issued FIRST (canary-pre-init), fly across the RAW
// barriers under MFMA+reduce+publish, checked with counted vmcnt at phase end.
// vmcnt ledger (no implicit drains anywhere in the loop):
//   waves 0-3: [8 sweep][3 stores] -> check vmcnt(3)
//   waves 4-7: [8 sweep][2 x-prefetch] -> check vmcnt(2) (vmcnt(0) at tail);
//              x regs staged this phase were retired by the PREVIOUS phase's
//              vmcnt(2) (everything older than its 2 newest retires in-order).
#define PHASE(G, X0, X1, X2, X3)                                               \
  {                                                                            \
    const bool doSweep = !((G) == 0 && t == 0) && !((G) == 1 && t == T_N - 1); \
    unsigned int sw[8];                                                        \
    const unsigned int* spd = ringc;                                           \
    if (doSweep) {                                                             \
      const int swt = t - 1 + (G);                                             \
      spd = ringc + (((G) ^ 1) * 4 + (swt & 3)) * 4096 + tid;                  \
      _Pragma("unroll")                                                        \
      for (int j = 0; j < 8; ++j) {                                            \
        sw[j] = CANARY;                                                        \
        ld_sc01_rw(&sw[j], spd + 512 * j);                                     \
      }                                                                        \
    }                                                                          \
    /* ---- MFMA (reads Apan staged in earlier phases) ---- */                 \
    f32x4 acc0 = {}, acc1 = {}, acc2 = {}, acc3 = {};                          \
    const int abase = (l & 15) * AP_STRIDE + wv * KW + ((l >> 4) << 3);        \
    _Pragma("unroll")                                                          \
    for (int kst = 0; kst < 6; ++kst) {                                        \
      bf16x8 a = *(const bf16x8*)(Apan + abase + kst * 32);                    \
      acc0 = __builtin_amdgcn_mfma_f32_16x16x32_bf16(a, Bh[kst][0], acc0,0,0,0);\
      acc1 = __builtin_amdgcn_mfma_f32_16x16x32_bf16(a, Bh[kst][1], acc1,0,0,0);\
      acc2 = __builtin_amdgcn_mfma_f32_16x16x32_bf16(a, Bh[kst][2], acc2,0,0,0);\
      acc3 = __builtin_amdgcn_mfma_f32_16x16x32_bf16(a, Bh[kst][3], acc3,0,0,0);\
    }                                                                          \
    if ((l >> 5) == (G)) {  /* group G's output rows live in these lanes */    \
      const int rb = ((l >> 4) & 1) << 2;                                      \
      *(f32x4*)(R + (size_t)(wv * COLS_H +  0 + (l & 15)) * RST + rb) = acc0;  \
      *(f32x4*)(R + (size_t)(wv * COLS_H + 16 + (l & 15)) * RST + rb) = acc1;  \
      *(f32x4*)(R + (size_t)(wv * COLS_H + 32 + (l & 15)) * RST + rb) = acc2;  \
      *(f32x4*)(R + (size_t)(wv * COLS_H + 48 + (l & 15)) * RST + rb) = acc3;  \
    }                                                                          \
    barrier_lds();  /* S1: LDS-only barrier; sweeps stay in flight */          \
    if (wv < 4) {                                                              \
      float v0 = pb0, v1 = pb1;                                                \
      _Pragma("unroll")                                                        \
      for (int kk = 0; kk < 8; ++kk) {                                         \
        v0 += R[(size_t)(kk * COLS_H + 2 * rcp)     * RST + rrow];             \
        v1 += R[(size_t)(kk * COLS_H + 2 * rcp + 1) * RST + rrow];             \
      }                                                                        \
      const float h0 = tanhf(v0), h1 = tanhf(v1);                              \
      const unsigned int pk =                                                  \
          (unsigned int)f2bf(h0) | ((unsigned int)f2bf(h1) << 16);             \
      /* 3 stores, asm-pinned AFTER the 8 sweep loads */                       \
      st_sc01(ringc + ((G) * 4 + (t & 3)) * 4096 + pubdw, pk);                 \
      st_sc01(ringc + ((G) * 4 + ((t + 2) & 3)) * 4096 + pubdw, CANARY);       \
      st_raw32((unsigned int*)(hs + ((size_t)t * 64 + b0 + (G) * 8 + rrow) * H_N \
                               + cbh + 2 * rcp), pk);                          \
      if (doSweep) {                                                           \
        asm volatile("s_waitcnt vmcnt(3)" ::: "memory");                       \
        __builtin_amdgcn_sched_barrier(0);                                     \
        bool bad = false;                                                      \
        _Pragma("unroll")                                                      \
        for (int j = 0; j < 8; ++j) bad |= (sw[j] == CANARY);                  \
        if (bad) {                                                             \
          int it = 0;                                                          \
          do {                                                                 \
            _Pragma("unroll")                                                  \
            for (int j = 0; j < 8; ++j) ld_sc01_nw(&sw[j], spd + 512 * j);     \
            asm volatile("s_waitcnt vmcnt(0)" ::: "memory");                   \
            __builtin_amdgcn_sched_barrier(0);                                 \
            bad = false;                                                       \
            _Pragma("unroll")                                                  \
            for (int j = 0; j < 8; ++j) bad |= (sw[j] == CANARY);              \
          } while (bad && ++it < POLL_CAP);                                    \
        }                                                                      \
      }                                                                        \
      if (t == T_N - 1) {                                                      \
        float2 fv; fv.x = h0; fv.y = h1;                                       \
        *(float2*)(hlast + (size_t)(b0 + (G) * 8 + rrow) * H_N + cbh + 2 * rcp) = fv; \
      }                                                                        \
    } else {                                                                   \
      if (t + 1 < T_N) {  /* stage x^G_{t+1}; regs retired by prev vmcnt(2) */ \
        const int u = tid & 255;                                               \
        *(bf16x8*)(Apan + ((G) * 8 + (u >> 6)) * AP_STRIDE + H_N + ((u & 63) << 3)) = \
            cvt8v(X0, X1);                                                     \
        *(bf16x8*)(Apan + ((G) * 8 + (u >> 6) + 4) * AP_STRIDE + H_N + ((u & 63) << 3)) = \
            cvt8v(X2, X3);                                                     \
      }                                                                        \
      int nIss = 0;                                                            \
      if (t + 2 < T_N) {  /* prefetch x^G_{t+2} */                             \
        const int u = tid & 255;                                               \
        const float* px = x + ((size_t)(t + 2) * 64 + b0 + (G) * 8 + (u >> 6)) * I_N \
                          + ((u & 63) << 3);                                   \
        ld4_rawf(&X0, px); ld4_rawf(&X1, px + 4);                              \
        ld4_rawf(&X2, px + 4 * I_N); ld4_rawf(&X3, px + 4 * I_N + 4);          \
        nIss = 4;                                                              \
      }                                                                        \
      if (doSweep) {                                                           \
        if (nIss) asm volatile("s_waitcnt vmcnt(4)" ::: "memory");             \
        else      asm volatile("s_waitcnt vmcnt(0)" ::: "memory");             \
        __builtin_amdgcn_sched_barrier(0);                                     \
        bool bad = false;                                                      \
        _Pragma("unroll")                                                      \
        for (int j = 0; j < 8; ++j) bad |= (sw[j] == CANARY);                  \
        if (bad) {                                                             \
          int it = 0;                                                          \
          do {                                                                 \
            _Pragma("unroll")                                                  \
            for (int j = 0; j < 8; ++j) ld_sc01_nw(&sw[j], spd + 512 * j);     \
            asm volatile("s_waitcnt vmcnt(0)" ::: "memory");                   \
            __builtin_amdgcn_sched_barrier(0);                                 \
            bad = false;                                                       \
            _Pragma("unroll")                                                  \
            for (int j = 0; j < 8; ++j) bad |= (sw[j] == CANARY);              \
          } while (bad && ++it < POLL_CAP);                                    \
        }                                                                      \
      }                                                                        \
    }                                                                          \
    if (doSweep) {  /* stage swept h (row j, dword-col tid) for next MFMA */   \
      _Pragma("unroll")                                                        \
      for (int j = 0; j < 8; ++j)                                              \
        *(unsigned int*)(Apan + ((((G) ^ 1) * 8) + j) * AP_STRIDE + (tid << 1)) = sw[j]; \
    }                                                                          \
    barrier_lds();  /* S2: LDS-only barrier */                                 \
  }

// Interleaved persistent scan. Grid 64 = 4 clusters x 16 members, 512 thr.
// Cluster c: batches [16c,16c+16) as groups A=[+0,+8) B=[+8,+16).
// Writes hs (bf16, [T][64][H]) and hlast (fp32). FC done by gemm_fc after.
__global__ __launch_bounds__(NTHR, 2) void rnn_scan(
    const float* __restrict__ x, const float* __restrict__ hidden,
    const float* __restrict__ Wih, const float* __restrict__ Whh,
    const float* __restrict__ bih, const float* __restrict__ bhh,
    unsigned short* __restrict__ hs, float* __restrict__ hlast,
    unsigned int* __restrict__ ring, unsigned int* __restrict__ flags)
{
  __shared__ __align__(16) unsigned short Apan[16 * AP_STRIDE];  // 49408 B
  __shared__ __align__(16) float R[8 * COLS_H * RST];            // 18432 B

  const int tid = threadIdx.x;
  const int l = tid & 63, wv = tid >> 6;
  const int bid = blockIdx.x;
  const int c = bid & 3;
  const int m = bid >> 2;
  const int b0 = c * 16;
  const int cbh = m * COLS_H;
  unsigned int* ringc = ring + (size_t)c * 2 * 4 * 4096;  // [2 grp][4 slot][4096 dw]
  unsigned int* bar = flags + c * 64;

  // ---- persistent recurrence weights: K=1536 = [Whh | Wih], 64 cols ----
  bf16x8 Bh[6][4];
  {
    const int kb0 = wv * KW + ((l >> 4) << 3);
#pragma unroll
    for (int kst = 0; kst < 6; ++kst) {
      const int k = kb0 + kst * 32;
#pragma unroll
      for (int f = 0; f < 4; ++f) {
        const int col = cbh + f * 16 + (l & 15);
        const float* src = (k < H_N) ? (Whh + (size_t)col * H_N + k)
                                     : (Wih + (size_t)col * I_N + (k - H_N));
        Bh[kst][f] = cvt8f(src);
      }
    }
  }
  const int rrow = (tid >> 5) & 7;
  const int rcp  = tid & 31;
  const float pb0 = bih[cbh + 2 * rcp]     + bhh[cbh + 2 * rcp];
  const float pb1 = bih[cbh + 2 * rcp + 1] + bhh[cbh + 2 * rcp + 1];
  const int pubdw = rrow * 512 + m * 32 + rcp;

  // ---- stage hidden rows 0-15 (both groups) ----
  {
    int q = tid;
#pragma unroll
    for (int i = 0; i < 4; ++i, q += NTHR) {
      const int row = q >> 7, col8 = (q & 127) << 3;
      *(bf16x8*)(Apan + row * AP_STRIDE + col8) =
          cvt8f(hidden + (size_t)(b0 + row) * H_N + col8);
    }
  }
  // ---- stage x_0 rows 0-15 ----
  {
    int q = tid;
#pragma unroll
    for (int i = 0; i < 2; ++i, q += NTHR) {
      const int row = q >> 6, col8 = (q & 63) << 3;
      *(bf16x8*)(Apan + row * AP_STRIDE + H_N + col8) =
          cvt8f(x + (size_t)(b0 + row) * I_N + col8);
    }
  }
  // ---- canary all 4 slots of both rings (own columns) ----
  if (tid < 256) {
#pragma unroll
    for (int s = 0; s < 8; ++s) st_sc01(ringc + s * 4096 + pubdw, CANARY);
  }
  asm volatile("s_waitcnt vmcnt(0)" ::: "memory");
  __syncthreads();
  // ---- member barrier (sc1 flags, capped) ----
  if (tid == 0) st_sc01(&bar[m], 1u);
  if (tid < NMEM) {
    int it = 0;
    while (ld_sc01(&bar[tid]) < 1u && ++it < HS_CAP)
      if (it > 64) __builtin_amdgcn_s_sleep(1);
  }
  // ---- prefetch x_1 for both groups (waves 4-7) ----
  float4 xA0, xA1, xA2, xA3, xB0, xB1, xB2, xB3;
  if (wv >= 4) {
    const int u = tid & 255;
    const float* pa = x + (size_t)(64 + b0 + (u >> 6)) * I_N + ((u & 63) << 3);
    ld4_rawf(&xA0, pa); ld4_rawf(&xA1, pa + 4);
    ld4_rawf(&xA2, pa + 4 * I_N); ld4_rawf(&xA3, pa + 4 * I_N + 4);
    const float* pb = x + (size_t)(64 + b0 + 8 + (u >> 6)) * I_N + ((u & 63) << 3);
    ld4_rawf(&xB0, pb); ld4_rawf(&xB1, pb + 4);
    ld4_rawf(&xB2, pb + 4 * I_N); ld4_rawf(&xB3, pb + 4 * I_N + 4);
  }
  __syncthreads();  // preamble drain (plain) — makes t=0 vmcnt ledger trivial

  for (int t = 0; t < T_N; ++t) {
    PHASE(0, xA0, xA1, xA2, xA3)   // group A step t
    PHASE(1, xB0, xB1, xB2, xB3)   // group B step t
  }
}

// FC GEMM: C[m][n] = sum_k hs[m][k]*Wfcb[n][k] + bfc[n]; fp32 out.
// M=32768, N=512, K=1024. 128x128 block tile, 4 waves, 64x64 wave tiles.
__global__ __launch_bounds__(256) void gemm_fc(const unsigned short* __restrict__ A,
                                               const unsigned short* __restrict__ Bt,
                                               const float* __restrict__ bias,
                                               float* __restrict__ C) {
  const int N = O_N, K = H_N;
  const int bm = blockIdx.x >> 2, bn = blockIdx.x & 3;
  const int l = threadIdx.x & 63, w = threadIdx.x >> 6;
  const int wr = w >> 1, wc = w & 1;
  const int row_a = bm * 128 + wr * 64 + (l & 15);
  const int row_b = bn * 128 + wc * 64 + (l & 15);
  const int koff = (l >> 4) * 8;
  f32x4 acc[4][4] = {};
  for (int k = 0; k < K; k += 32) {
    bf16x8 a[4], b[4];
#pragma unroll
    for (int i = 0; i < 4; i++)
      a[i] = *(const bf16x8*)(A + (size_t)(row_a + i * 16) * K + k + koff);
#pragma unroll
    for (int i = 0; i < 4; i++)
      b[i] = *(const bf16x8*)(Bt + (size_t)(row_b + i * 16) * K + k + koff);
#pragma unroll
    for (int i = 0; i < 4; i++)
#pragma unroll
      for (int j = 0; j < 4; j++)
        acc[i][j] = __builtin_amdgcn_mfma_f32_16x16x32_bf16(a[i], b[j], acc[i][j], 0, 0, 0);
  }
  const int orow = bm * 128 + wr * 64 + ((l >> 4) << 2);
  const int ocol = bn * 128 + wc * 64 + (l & 15);
#pragma unroll
  for (int i = 0; i < 4; i++)
#pragma unroll
    for (int j = 0; j < 4; j++) {
      const int r0 = orow + i * 16, c0 = ocol + j * 16;
      const float bv = bias[c0];
#pragma unroll
      for (int r = 0; r < 4; r++)
        C[(size_t)(r0 + r) * N + c0] = acc[i][j][r] + bv;
    }
}

// fp32 -> bf16 convert (for Wfc)
__global__ __launch_bounds__(256) void cvt8(const float* __restrict__ s,
                                            unsigned short* __restrict__ d, long n) {
  long i = ((long)blockIdx.x * blockDim.x + threadIdx.x) * 8;
  if (i < n) *(bf16x8*)(d + i) = cvt8f(s + i);
}

extern "C" void kernel_launch(void* const* d_in, const int* in_sizes, int n_in,
                              void* d_out, int out_size, void* d_ws, size_t ws_size,
                              hipStream_t stream) {
  const float* x   = (const float*)d_in[0];
  const float* hid = (const float*)d_in[1];
  const float* Wih = (const float*)d_in[2];
  const float* Whh = (const float*)d_in[3];
  const float* bih = (const float*)d_in[4];
  const float* bhh = (const float*)d_in[5];
  const float* Wfc = (const float*)d_in[6];
  const float* bfc = (const float*)d_in[7];

  float* out   = (float*)d_out;                      // fp32 [T*B][O]
  float* hlast = out + (size_t)32768 * 512;          // fp32 [B][H]

  unsigned int*   flags = (unsigned int*)d_ws;                       // 4 KB
  unsigned int*   ring  = (unsigned int*)((char*)d_ws + 4096);       // 512 KB
  unsigned short* Wfcb  = (unsigned short*)((char*)d_ws + 4096 + 524288);  // 1 MB
  unsigned short* hsb   = Wfcb + (size_t)512 * 1024;                 // 67.1 MB

  (void)hipMemsetAsync(flags, 0, 4096, stream);
  cvt8<<<256, 256, 0, stream>>>(Wfc, Wfcb, (long)512 * 1024);
  rnn_scan<<<64, NTHR, 0, stream>>>(x, hid, Wih, Whh, bih, bhh, hsb, hlast, ring, flags);
  gemm_fc<<<1024, 256, 0, stream>>>(hsb, Wfcb, bfc, out);
}